// Round 2
// baseline (209.476 us; speedup 1.0000x reference)
//
#include <hip/hip_runtime.h>
#include <hip/hip_bf16.h>

// Problem constants
#define B_      1024
#define CIN     9
#define T0_     2048
#define C1_     16
#define C2_     32
#define RT_     512
#define NNODES  (B_ * RT_)     // 524288
#define HID_    128
#define OUTF_   64

typedef __attribute__((ext_vector_type(8))) __bf16 bf16x8;
typedef __attribute__((ext_vector_type(4))) float f32x4;
typedef __attribute__((ext_vector_type(8))) unsigned short us8;

// ---------- helpers ----------
__device__ __forceinline__ float bf2f(unsigned short u) {
    union { unsigned int i; float f; } c; c.i = ((unsigned int)u) << 16; return c.f;
}
// round-half-up bf16 (2 ops)
__device__ __forceinline__ unsigned short f2bf1(float f) {
    union { float f; unsigned int i; } c; c.f = f;
    return (unsigned short)((c.i + 0x8000u) >> 16);
}
// packed pair: low short = bf16(lo), high short = bf16(hi); 2 adds + 1 v_perm
__device__ __forceinline__ unsigned int f2bf2(float lo, float hi) {
    union { float f; unsigned int i; } a, b; a.f = lo; b.f = hi;
    return __builtin_amdgcn_perm(b.i + 0x8000u, a.i + 0x8000u, 0x07060302u);
}
__device__ __forceinline__ float dinv_of(int r) {
    return (r == 0 || r == RT_ - 1) ? 0.70710678118f : 0.57735026919f;
}

// Exact (x3-scaled) band B-fragment for boundary tiles: coefficients split
// hi+lo in bf16 so two accumulating MFMAs reproduce f32-accurate weights.
// Lane roles: n = lane&15 (output node within tile), g = lane>>4 (K-group).
__device__ __forceinline__ void band3(int rbase, int n, int g, bf16x8* hi, bf16x8* lo) {
    const int r = rbase + n;
    float cl = 0.f, cm = 0.f, cr = 0.f;
    if (r >= 0 && r < RT_) {
        const float dm = dinv_of(r);
        cl = (r > 0)        ? 3.f * dm * dinv_of(r - 1) : 0.f;
        cm = 3.f * dm * dm;
        cr = (r < RT_ - 1)  ? 3.f * dm * dinv_of(r + 1) : 0.f;
    }
    union { us8 u; bf16x8 b; } h, l;
    #pragma unroll
    for (int j = 0; j < 8; j++) {
        const int d = (g * 8 + j) - n;
        const float c = (d == 0) ? cl : (d == 1) ? cm : (d == 2) ? cr : 0.f;
        const unsigned short ch = f2bf1(c);
        h.u[j] = ch;
        l.u[j] = f2bf1(c - bf2f(ch));
    }
    *hi = h.b; *lo = l.b;
}

// ---------- kernel R: repack all weights into bf16 MFMA fragment order (32 blocks) ----------
__global__ __launch_bounds__(256) void repack_w(
    const float* __restrict__ W1g, const float* __restrict__ W2g,
    const float* __restrict__ Wc1g, const float* __restrict__ Wc2g,
    unsigned short* __restrict__ Wb1, unsigned short* __restrict__ Wb2,
    unsigned short* __restrict__ Wc1, unsigned short* __restrict__ Wc2)
{
    const int tid = threadIdx.x;
    const int bid = blockIdx.x;
    if (bid < 8) {                                     // W1: 4096 elems, 512/block
        for (int i = tid; i < 512; i += 256) {
            int s = bid * 512 + i;
            int k = s >> 7, f = s & 127;
            int lane = ((k >> 3) << 4) + (f & 15);
            int e = (((f >> 4) * 64) + lane) * 8 + (k & 7);
            Wb1[e] = f2bf1(W1g[s]);
        }
    } else if (bid < 24) {                             // W2: 16384 elems, 1024/block
        for (int i = tid; i < 1024; i += 256) {
            int s = (bid - 8) * 1024 + i;
            int k = s >> 7, f = s & 127;
            int ks = k >> 5, lane = (((k >> 3) & 3) << 4) + (f & 15);
            int e = ((ks * 8 + (f >> 4)) * 64 + lane) * 8 + (k & 7);
            Wb2[e] = f2bf1(W2g[s]);
        }
    } else if (bid < 28) {                             // Wc1: 1536 elems, 384/block
        for (int i = tid; i < 384; i += 256) {
            int e = (bid - 24) * 384 + i;
            int j = e & 7, lane = (e >> 3) & 63, ks = e >> 9;
            int kk = ks * 32 + (lane >> 4) * 8 + j;
            int k = kk >> 4, ci = kk & 15, co = lane & 15;
            Wc1[e] = (k < 5 && ci < CIN) ? f2bf1(Wc1g[(co * CIN + ci) * 5 + k]) : 0;
        }
    } else {                                           // Wc2: 3072 elems, 768/block
        for (int i = tid; i < 768; i += 256) {
            int e = (bid - 28) * 768 + i;
            int j = e & 7, lane = (e >> 3) & 63, nt = (e >> 9) & 1, ks = e >> 10;
            int kk = ks * 32 + (lane >> 4) * 8 + j;
            int k = kk >> 4, ci = kk & 15, co = nt * 16 + (lane & 15);
            Wc2[e] = (k < 5) ? f2bf1(Wc2g[(co * C1_ + ci) * 5 + k]) : 0;
        }
    }
}

// ---------- MEGAKERNEL ----------
// R13: R12 structure (GCN stencils on MFMA via banded matrix) but back to
// __launch_bounds__(256,3). R12's (256,4) capped the unified file at 128
// regs/thread; with 64 AGPRs of acc that left 64 arch VGPRs -> scratch spills
// (WRITE_SIZE 2MB -> 33MB, spill fills on the E/F/G critical path, 91 -> 98us).
// At (256,3) the register budget (~170) fits the working set spill-free.
//
// LDS overlay (bytes):
//   xs    [0, 26496)      552*24 shorts    A,B
//   y1ext [26496, 39936)  280*24 shorts    B,C
//   y2T   [0, 10752)      32*168 shorts    C,D   (conv2 out, TRANSPOSED [ch][node])
//   As1   [10752, 19968)  144*32 shorts    D..slices  ([node][feat32])
//   HTs   [19968, 29696)  32*152 shorts    slices     (H slice, TRANSPOSED [feat][node])
//   A2s   [29696, 37888)  128*32 shorts    slices     ([node][feat-slice32])
//   bls1  [37888, 38400); bls2 [38400, 38912)   (written during D)
__global__ __launch_bounds__(256, 3) void mega(
    const float* __restrict__ x,             // [B][9][2048] fp32
    const unsigned short* __restrict__ Wc1,  // conv1 B-frags
    const unsigned short* __restrict__ Wc2,  // conv2 B-frags
    const unsigned short* __restrict__ Wb1,  // gcn1 A-frags (W1^T)
    const unsigned short* __restrict__ Wb2,  // gcn2 B-frags
    const float* __restrict__ c1b, const float* __restrict__ c2b,
    const float* __restrict__ g1b, const float* __restrict__ g2b,
    float* __restrict__ partials)            // [B][4][128] fp32
{
    __shared__ __align__(16) unsigned char lds[38912];
    unsigned short* xs    = (unsigned short*)(lds);
    unsigned short* y1ext = (unsigned short*)(lds + 26496);
    unsigned short* y2T   = (unsigned short*)(lds);
    unsigned short* As1   = (unsigned short*)(lds + 10752);
    unsigned short* HTs   = (unsigned short*)(lds + 19968);
    unsigned short* A2s   = (unsigned short*)(lds + 29696);
    float* bls1 = (float*)(lds + 37888);
    float* bls2 = (float*)(lds + 38400);

    const int tid = threadIdx.x;
    const int b = blockIdx.x >> 2;
    const int r0 = (blockIdx.x & 3) * 128;

    const int lane = tid & 63, wave = tid >> 6;
    const int m = lane & 15, q = lane >> 4;
    const int wp = wave & 1;               // feature-tile parity for D/E/F work split

    // prebuilt conv1 fragments: coalesced 16B loads
    bf16x8 wfB[3];
    #pragma unroll
    for (int ks = 0; ks < 3; ks++) wfB[ks] = *(const bf16x8*)(Wc1 + (ks * 64 + lane) * 8);

    // ---- phase A: stage x as bf16 time-major: xs[s][ci], s=0..551, xt=4r0-14+s
    {
        const float* xb = x + (size_t)b * CIN * T0_;
        const int xbase = 4 * r0 - 14;
        for (int s = tid; s < 552; s += 256) {
            const int xt = xbase + s;
            union { us8 v; unsigned int u[4]; } o0, o1;
            if (xt >= 0 && xt < T0_) {
                float xv[9];
                #pragma unroll
                for (int ci = 0; ci < 9; ci++) xv[ci] = xb[ci * T0_ + xt];
                o0.u[0] = f2bf2(xv[0], xv[1]); o0.u[1] = f2bf2(xv[2], xv[3]);
                o0.u[2] = f2bf2(xv[4], xv[5]); o0.u[3] = f2bf2(xv[6], xv[7]);
                o1.u[0] = f2bf2(xv[8], 0.f);   o1.u[1] = o1.u[2] = o1.u[3] = 0;
            } else {
                o0.u[0] = o0.u[1] = o0.u[2] = o0.u[3] = 0;
                o1.u[0] = o1.u[1] = o1.u[2] = o1.u[3] = 0;
            }
            *(us8*)(xs + s * 24) = o0.v;
            *(us8*)(xs + s * 24 + 8) = o1.v;
        }
    }
    // conv2 fragments loaded here: latency covered by phase A tail / barrier
    bf16x8 wfC[3][2];
    #pragma unroll
    for (int ks = 0; ks < 3; ks++)
        #pragma unroll
        for (int nt = 0; nt < 2; nt++)
            wfC[ks][nt] = *(const bf16x8*)(Wc2 + ((ks * 2 + nt) * 64 + lane) * 8);
    __syncthreads();

    // ---- phase B: conv1 MFMA + relu + pool -> y1ext (zero for t1 outside [0,1024))
    {
        const float bv = c1b[m];
        const int t1base = 2 * r0 - 6;
        for (int mt = wave; mt < 34; mt += 4) {
            f32x4 acc = {};
            #pragma unroll
            for (int ks = 0; ks < 3; ks++) {
                const int row = mt * 16 + m + ks * 2 + (q >> 1);
                const bf16x8 af = *(const bf16x8*)(xs + row * 24 + (q & 1) * 8);
                acc = __builtin_amdgcn_mfma_f32_16x16x32_bf16(af, wfB[ks], acc, 0, 0, 0);
            }
            const int prow = mt * 8 + q * 2;     // y1ext row; t1 = t1base + prow
            const int t1a = t1base + prow, t1b = t1a + 1;
            const float p0 = fmaxf(fmaxf(acc[0], acc[1]) + bv, 0.f);
            const float p1 = fmaxf(fmaxf(acc[2], acc[3]) + bv, 0.f);
            if (prow < 268)
                y1ext[prow * 24 + m] = (t1a >= 0 && t1a < 1024) ? f2bf1(p0) : (unsigned short)0;
            if (prow + 1 < 268)
                y1ext[(prow + 1) * 24 + m] = (t1b >= 0 && t1b < 1024) ? f2bf1(p1) : (unsigned short)0;
        }
        for (int idx = tid; idx < 288; idx += 256) y1ext[268 * 24 + idx] = 0;  // rows 268..279
    }
    __syncthreads();

    // ---- phase C: conv2 MFMA + relu + pool -> y2T (TRANSPOSED: [ch][node-col]),
    //      cols: node r0-2+c, c=0..131; pad cols 132..163 zeroed (stencil window safety)
    {
        for (int i = tid; i < 512; i += 256) {
            const int row = i >> 4, c = i & 15;
            *(unsigned int*)(y2T + row * 168 + 132 + c * 2) = 0u;
        }
        const float bv0 = c2b[m], bv1 = c2b[16 + m];
        for (int mt = wave; mt < 17; mt += 4) {
            f32x4 a0 = {}, a1 = {};
            #pragma unroll
            for (int ks = 0; ks < 3; ks++) {
                const int row = mt * 16 + m + ks * 2 + (q >> 1);
                const bf16x8 af = *(const bf16x8*)(y1ext + row * 24 + (q & 1) * 8);
                a0 = __builtin_amdgcn_mfma_f32_16x16x32_bf16(af, wfC[ks][0], a0, 0, 0, 0);
                a1 = __builtin_amdgcn_mfma_f32_16x16x32_bf16(af, wfC[ks][1], a1, 0, 0, 0);
            }
            const int nrow = mt * 8 + q * 2;
            if (nrow < 132) {
                y2T[m * 168 + nrow]        = f2bf1(fmaxf(fmaxf(a0[0], a0[1]) + bv0, 0.f));
                y2T[(16 + m) * 168 + nrow] = f2bf1(fmaxf(fmaxf(a1[0], a1[1]) + bv1, 0.f));
            }
            if (nrow + 1 < 132) {
                y2T[m * 168 + nrow + 1]        = f2bf1(fmaxf(fmaxf(a0[2], a0[3]) + bv0, 0.f));
                y2T[(16 + m) * 168 + nrow + 1] = f2bf1(fmaxf(fmaxf(a1[2], a1[3]) + bv1, 0.f));
            }
        }
    }
    __syncthreads();

    // generic interior band fragment: ones at k-n in [0,2] (exact in bf16);
    // stencil result gets a *1/3 f32 post-scale.
    union { us8 u; bf16x8 b; } bones;
    #pragma unroll
    for (int j = 0; j < 8; j++) {
        const int d = (q * 8 + j) - m;
        bones.u[j] = (d >= 0 && d <= 2) ? (unsigned short)0x3F80 : (unsigned short)0;
    }
    const f32x4 zz = {};

    // ---- phase D (gcn1 aggregation via MFMA): As1[node][feat32] = Band1 @ y2
    //      As1 row i <-> node r0-1+i (rows 130..143 finite don't-care)
    if (tid < 128) { bls1[tid] = g1b[tid]; bls2[tid] = g2b[tid]; }
    for (int idx = wave; idx < 18; idx += 4) {
        const int ot = idx >> 1;             // output node-tile 0..8; ftl = wp
        const bf16x8 af = *(const bf16x8*)(y2T + (wp * 16 + m) * 168 + ot * 16 + q * 8);
        f32x4 o;
        if ((r0 == 0 && ot == 0) || (r0 == 384 && ot >= 7)) {
            bf16x8 bh, bl; band3(r0 - 1 + ot * 16, m, q, &bh, &bl);
            o = __builtin_amdgcn_mfma_f32_16x16x32_bf16(af, bh, zz, 0, 0, 0);
            o = __builtin_amdgcn_mfma_f32_16x16x32_bf16(af, bl, o, 0, 0, 0);
        } else {
            o = __builtin_amdgcn_mfma_f32_16x16x32_bf16(af, bones.b, zz, 0, 0, 0);
        }
        union { ushort4 s; unsigned int u[2]; } w;
        w.u[0] = f2bf2(o[0] * (1.f / 3.f), o[1] * (1.f / 3.f));
        w.u[1] = f2bf2(o[2] * (1.f / 3.f), o[3] * (1.f / 3.f));
        *(ushort4*)(As1 + (ot * 16 + m) * 32 + wp * 16 + q * 4) = w.s;
    }
    __syncthreads();

    // ---- phases E/F/G in 4 feature-slices of 32 (gcn2 acc accumulates over K)
    f32x4 acc[8][2] = {};
    bf16x8 wfE = *(const bf16x8*)(Wb1 + ((size_t)(wp * 64 + lane)) * 8);
    bf16x8 bwA = *(const bf16x8*)(Wb2 + ((size_t)((wave * 2 + 0) * 64 + lane)) * 8);
    bf16x8 bwB = *(const bf16x8*)(Wb2 + ((size_t)((wave * 2 + 1) * 64 + lane)) * 8);

    for (int ks = 0; ks < 4; ks++) {
        // E: HTs[feat-in-slice][node] = relu(W1^T-slice @ As1^T + b1-slice)
        {
            const float4 bv = *(const float4*)&bls1[ks * 32 + wp * 16 + q * 4];
            for (int idx = wave; idx < 18; idx += 4) {
                const int nt = idx >> 1;
                const bf16x8 bfr = *(const bf16x8*)(As1 + (nt * 16 + m) * 32 + q * 8);
                f32x4 o = __builtin_amdgcn_mfma_f32_16x16x32_bf16(wfE, bfr, zz, 0, 0, 0);
                unsigned short* hb = HTs + (wp * 16 + q * 4) * 152 + nt * 16 + m;
                hb[0]   = f2bf1(fmaxf(o[0] + bv.x, 0.f));
                hb[152] = f2bf1(fmaxf(o[1] + bv.y, 0.f));
                hb[304] = f2bf1(fmaxf(o[2] + bv.z, 0.f));
                hb[456] = f2bf1(fmaxf(o[3] + bv.w, 0.f));
            }
        }
        // prefetch next slice's weight frags (latency hidden under F+G)
        const int ksn = (ks < 3) ? ks + 1 : 3;
        bf16x8 nE = *(const bf16x8*)(Wb1 + ((size_t)((2 * ksn + wp) * 64 + lane)) * 8);
        bf16x8 nA = *(const bf16x8*)(Wb2 + ((size_t)((ksn * 8 + wave * 2 + 0) * 64 + lane)) * 8);
        bf16x8 nB = *(const bf16x8*)(Wb2 + ((size_t)((ksn * 8 + wave * 2 + 1) * 64 + lane)) * 8);
        __syncthreads();

        // F: A2s[node][feat-slice32] = Band2 @ H-slice  (via MFMA)
        for (int idx = wave; idx < 16; idx += 4) {
            const int nt = idx >> 1;
            const bf16x8 af = *(const bf16x8*)(HTs + (wp * 16 + m) * 152 + nt * 16 + q * 8);
            f32x4 o;
            if ((r0 == 0 && nt == 0) || (r0 == 384 && nt == 7)) {
                bf16x8 bh, bl; band3(r0 + nt * 16, m, q, &bh, &bl);
                o = __builtin_amdgcn_mfma_f32_16x16x32_bf16(af, bh, zz, 0, 0, 0);
                o = __builtin_amdgcn_mfma_f32_16x16x32_bf16(af, bl, o, 0, 0, 0);
            } else {
                o = __builtin_amdgcn_mfma_f32_16x16x32_bf16(af, bones.b, zz, 0, 0, 0);
            }
            union { ushort4 s; unsigned int u[2]; } w;
            w.u[0] = f2bf2(o[0] * (1.f / 3.f), o[1] * (1.f / 3.f));
            w.u[1] = f2bf2(o[2] * (1.f / 3.f), o[3] * (1.f / 3.f));
            *(ushort4*)(A2s + (nt * 16 + m) * 32 + wp * 16 + q * 4) = w.s;
        }
        __syncthreads();

        // G: acc += A2-slice @ W2-slice
        #pragma unroll
        for (int nt = 0; nt < 8; nt++) {
            const bf16x8 af = *(const bf16x8*)(A2s + (nt * 16 + m) * 32 + q * 8);
            acc[nt][0] = __builtin_amdgcn_mfma_f32_16x16x32_bf16(af, bwA, acc[nt][0], 0, 0, 0);
            acc[nt][1] = __builtin_amdgcn_mfma_f32_16x16x32_bf16(af, bwB, acc[nt][1], 0, 0, 0);
        }
        wfE = nE; bwA = nA; bwB = nB;
        __syncthreads();
    }

    // ---- epilogue: bias/relu + per-tile column sums, plain stores (no atomics)
    {
        const float bb0 = bls2[wave * 32 + m];
        const float bb1 = bls2[wave * 32 + 16 + m];
        float s0 = 0.f, s1 = 0.f;
        #pragma unroll
        for (int nt = 0; nt < 8; nt++)
            #pragma unroll
            for (int rgi = 0; rgi < 4; rgi++) {
                s0 += fmaxf(acc[nt][0][rgi] + bb0, 0.f);
                s1 += fmaxf(acc[nt][1][rgi] + bb1, 0.f);
            }
        s0 += __shfl_xor(s0, 16, 64); s0 += __shfl_xor(s0, 32, 64);
        s1 += __shfl_xor(s1, 16, 64); s1 += __shfl_xor(s1, 32, 64);
        if (lane < 16) {
            float* p = partials + (size_t)blockIdx.x * 128 + wave * 32;
            p[m] = s0;
            p[16 + m] = s1;
        }
    }
}

// ---------- kernel 5: mean over RT + FC ----------
__global__ __launch_bounds__(128) void fc_kernel(
    const float* __restrict__ partials, const float* __restrict__ fw,
    const float* __restrict__ fb, float* __restrict__ out)
{
    __shared__ float sm[128];
    const int b = blockIdx.x, tid = threadIdx.x;
    float s = 0.f;
    #pragma unroll
    for (int t = 0; t < 4; t++) s += partials[((b << 2) + t) * 128 + tid];
    sm[tid] = s * (1.0f / 512.0f);
    __syncthreads();
    if (tid < 64) {
        float acc = fb[tid];
        #pragma unroll 8
        for (int f = 0; f < 128; f++) acc += sm[f] * fw[f * 64 + tid];
        out[b * 64 + tid] = acc;
    }
}

extern "C" void kernel_launch(void* const* d_in, const int* in_sizes, int n_in,
                              void* d_out, int out_size, void* d_ws, size_t ws_size,
                              hipStream_t stream)
{
    const float* x   = (const float*)d_in[0];
    const float* w1  = (const float*)d_in[1];
    const float* b1  = (const float*)d_in[2];
    const float* w2  = (const float*)d_in[3];
    const float* b2  = (const float*)d_in[4];
    const float* g1w = (const float*)d_in[5];
    const float* g1b = (const float*)d_in[6];
    const float* g2w = (const float*)d_in[7];
    const float* g2b = (const float*)d_in[8];
    const float* fw  = (const float*)d_in[9];
    const float* fb  = (const float*)d_in[10];

    char* ws = (char*)d_ws;
    float* partials     = (float*)(ws);                           // [B][4][128] fp32 = 2MB
    unsigned short* Wb1 = (unsigned short*)(ws + 2097152);        // 4096 elems
    unsigned short* Wb2 = (unsigned short*)(ws + 2097152 + 16384);// 16384 elems
    unsigned short* Wc1 = (unsigned short*)(ws + 2097152 + 65536);// 1536 elems
    unsigned short* Wc2 = (unsigned short*)(ws + 2097152 + 81920);// 3072 elems
    float* out = (float*)d_out;

    repack_w<<<32, 256, 0, stream>>>(g1w, g2w, w1, w2, Wb1, Wb2, Wc1, Wc2);
    mega<<<NNODES / 128, 256, 0, stream>>>(x, Wc1, Wc2, Wb1, Wb2,
                                           b1, b2, g1b, g2b, partials);
    fc_kernel<<<B_, 128, 0, stream>>>(partials, fw, fb, out);
}

// Round 3
// 182.768 us; speedup vs baseline: 1.1461x; 1.1461x over previous
//
#include <hip/hip_runtime.h>
#include <hip/hip_bf16.h>

// Problem constants
#define B_      1024
#define CIN     9
#define T0_     2048
#define C1_     16
#define C2_     32
#define RT_     512
#define NNODES  (B_ * RT_)     // 524288
#define HID_    128
#define OUTF_   64

typedef __attribute__((ext_vector_type(8))) __bf16 bf16x8;
typedef __attribute__((ext_vector_type(4))) float f32x4;
typedef __attribute__((ext_vector_type(8))) unsigned short us8;

// ---------- helpers ----------
__device__ __forceinline__ float bf2f(unsigned short u) {
    union { unsigned int i; float f; } c; c.i = ((unsigned int)u) << 16; return c.f;
}
// round-half-up bf16 (2 ops)
__device__ __forceinline__ unsigned short f2bf1(float f) {
    union { float f; unsigned int i; } c; c.f = f;
    return (unsigned short)((c.i + 0x8000u) >> 16);
}
// packed pair: low short = bf16(lo), high short = bf16(hi); 2 adds + 1 v_perm
__device__ __forceinline__ unsigned int f2bf2(float lo, float hi) {
    union { float f; unsigned int i; } a, b; a.f = lo; b.f = hi;
    return __builtin_amdgcn_perm(b.i + 0x8000u, a.i + 0x8000u, 0x07060302u);
}
__device__ __forceinline__ float dinv_of(int r) {
    return (r == 0 || r == RT_ - 1) ? 0.70710678118f : 0.57735026919f;
}

// ---------- kernel R: repack all weights into bf16 MFMA fragment order (32 blocks) ----------
__global__ __launch_bounds__(256) void repack_w(
    const float* __restrict__ W1g, const float* __restrict__ W2g,
    const float* __restrict__ Wc1g, const float* __restrict__ Wc2g,
    unsigned short* __restrict__ Wb1, unsigned short* __restrict__ Wb2,
    unsigned short* __restrict__ Wc1, unsigned short* __restrict__ Wc2)
{
    const int tid = threadIdx.x;
    const int bid = blockIdx.x;
    if (bid < 8) {                                     // W1: 4096 elems, 512/block
        for (int i = tid; i < 512; i += 256) {
            int s = bid * 512 + i;
            int k = s >> 7, f = s & 127;
            int lane = ((k >> 3) << 4) + (f & 15);
            int e = (((f >> 4) * 64) + lane) * 8 + (k & 7);
            Wb1[e] = f2bf1(W1g[s]);
        }
    } else if (bid < 24) {                             // W2: 16384 elems, 1024/block
        for (int i = tid; i < 1024; i += 256) {
            int s = (bid - 8) * 1024 + i;
            int k = s >> 7, f = s & 127;
            int ks = k >> 5, lane = (((k >> 3) & 3) << 4) + (f & 15);
            int e = ((ks * 8 + (f >> 4)) * 64 + lane) * 8 + (k & 7);
            Wb2[e] = f2bf1(W2g[s]);
        }
    } else if (bid < 28) {                             // Wc1: 1536 elems, 384/block
        for (int i = tid; i < 384; i += 256) {
            int e = (bid - 24) * 384 + i;
            int j = e & 7, lane = (e >> 3) & 63, ks = e >> 9;
            int kk = ks * 32 + (lane >> 4) * 8 + j;
            int k = kk >> 4, ci = kk & 15, co = lane & 15;
            Wc1[e] = (k < 5 && ci < CIN) ? f2bf1(Wc1g[(co * CIN + ci) * 5 + k]) : 0;
        }
    } else {                                           // Wc2: 3072 elems, 768/block
        for (int i = tid; i < 768; i += 256) {
            int e = (bid - 28) * 768 + i;
            int j = e & 7, lane = (e >> 3) & 63, nt = (e >> 9) & 1, ks = e >> 10;
            int kk = ks * 32 + (lane >> 4) * 8 + j;
            int k = kk >> 4, ci = kk & 15, co = nt * 16 + (lane & 15);
            Wc2[e] = (k < 5) ? f2bf1(Wc2g[(co * C1_ + ci) * 5 + k]) : 0;
        }
    }
}

// ---------- MEGAKERNEL ----------
// R14: R11's quarter-major structure (node-major layouts, VALU stencils) with
// occupancy pushed to 4 blocks/CU:
//  - per-quarter gcn2 reduction: acc is complete after each quarter's G (full
//    K=128), so reduce immediately -> acc[2][2] (16 regs) instead of [8][2] (64)
//  - E moved inside quarters: 34-row H slab per quarter (+33% E MFMAs, cheap)
//    -> H shrinks 35,360B -> 9,248B slab
//  - A2q stride 152->136; biases from global (loop-invariant) instead of LDS
//  LDS peak 40,032B -> 4 blocks/CU; unified regs ~95 < 128 cap -> no spill.
//
// LDS overlay (bytes), all row strides 16B multiples:
//   xs    [0, 26496)       552*24 shorts   A,B
//   y1ext [26496, 39936)   280*24 shorts   B,C
//   y2loc [0, 10560)       132*40 shorts   C,D   (node-major)
//   As1   [10560, 22080)   144*40 shorts   D..E
//   Hq    [22080, 31328)   34*136 shorts   E,F (per-quarter slab)
//   A2q   [31328, 40032)   32*136 shorts   F,G (per-quarter)
__global__ __launch_bounds__(256, 4) void mega(
    const float* __restrict__ x,             // [B][9][2048] fp32
    const unsigned short* __restrict__ Wc1,  // conv1 B-frags
    const unsigned short* __restrict__ Wc2,  // conv2 B-frags
    const unsigned short* __restrict__ Wb1,  // gcn1 A-frags (W1^T)
    const unsigned short* __restrict__ Wb2,  // gcn2 B-frags
    const float* __restrict__ c1b, const float* __restrict__ c2b,
    const float* __restrict__ g1b, const float* __restrict__ g2b,
    float* __restrict__ partials)            // [B][4][128] fp32
{
    __shared__ __align__(16) unsigned char lds[40032];
    unsigned short* xs    = (unsigned short*)(lds);
    unsigned short* y1ext = (unsigned short*)(lds + 26496);
    unsigned short* y2loc = (unsigned short*)(lds);
    unsigned short* As1   = (unsigned short*)(lds + 10560);
    unsigned short* Hq    = (unsigned short*)(lds + 22080);
    unsigned short* A2q   = (unsigned short*)(lds + 31328);

    const int tid = threadIdx.x;
    const int b = blockIdx.x >> 2;
    const int r0 = (blockIdx.x & 3) * 128;

    const int lane = tid & 63, wave = tid >> 6;
    const int m = lane & 15, q = lane >> 4;
    const int ft0 = wave * 2;              // this wave's gcn1 output feat-tiles

    // prebuilt conv1 fragments: coalesced 16B loads
    bf16x8 wfB[3];
    #pragma unroll
    for (int ks = 0; ks < 3; ks++) wfB[ks] = *(const bf16x8*)(Wc1 + (ks * 64 + lane) * 8);

    // ---- phase A: stage x as bf16 time-major: xs[s][ci], s=0..551, xt=4r0-14+s
    {
        const float* xb = x + (size_t)b * CIN * T0_;
        const int xbase = 4 * r0 - 14;
        for (int s = tid; s < 552; s += 256) {
            const int xt = xbase + s;
            union { us8 v; unsigned int u[4]; } o0, o1;
            if (xt >= 0 && xt < T0_) {
                float xv[9];
                #pragma unroll
                for (int ci = 0; ci < 9; ci++) xv[ci] = xb[ci * T0_ + xt];
                o0.u[0] = f2bf2(xv[0], xv[1]); o0.u[1] = f2bf2(xv[2], xv[3]);
                o0.u[2] = f2bf2(xv[4], xv[5]); o0.u[3] = f2bf2(xv[6], xv[7]);
                o1.u[0] = f2bf2(xv[8], 0.f);   o1.u[1] = o1.u[2] = o1.u[3] = 0;
            } else {
                o0.u[0] = o0.u[1] = o0.u[2] = o0.u[3] = 0;
                o1.u[0] = o1.u[1] = o1.u[2] = o1.u[3] = 0;
            }
            *(us8*)(xs + s * 24) = o0.v;
            *(us8*)(xs + s * 24 + 8) = o1.v;
        }
    }
    // conv2 fragments loaded here: latency covered by phase A tail / barrier
    bf16x8 wfC[3][2];
    #pragma unroll
    for (int ks = 0; ks < 3; ks++)
        #pragma unroll
        for (int nt = 0; nt < 2; nt++)
            wfC[ks][nt] = *(const bf16x8*)(Wc2 + ((ks * 2 + nt) * 64 + lane) * 8);
    __syncthreads();

    // ---- phase B: conv1 MFMA + relu + pool -> y1ext (zero for t1 outside [0,1024))
    {
        const float bv = c1b[m];
        const int t1base = 2 * r0 - 6;
        for (int mt = wave; mt < 34; mt += 4) {
            f32x4 acc = {};
            #pragma unroll
            for (int ks = 0; ks < 3; ks++) {
                const int row = mt * 16 + m + ks * 2 + (q >> 1);
                const bf16x8 af = *(const bf16x8*)(xs + row * 24 + (q & 1) * 8);
                acc = __builtin_amdgcn_mfma_f32_16x16x32_bf16(af, wfB[ks], acc, 0, 0, 0);
            }
            const int prow = mt * 8 + q * 2;     // y1ext row; t1 = t1base + prow
            const int t1a = t1base + prow, t1b = t1a + 1;
            const float p0 = fmaxf(fmaxf(acc[0], acc[1]) + bv, 0.f);
            const float p1 = fmaxf(fmaxf(acc[2], acc[3]) + bv, 0.f);
            if (prow < 268)
                y1ext[prow * 24 + m] = (t1a >= 0 && t1a < 1024) ? f2bf1(p0) : (unsigned short)0;
            if (prow + 1 < 268)
                y1ext[(prow + 1) * 24 + m] = (t1b >= 0 && t1b < 1024) ? f2bf1(p1) : (unsigned short)0;
        }
        for (int idx = tid; idx < 288; idx += 256) y1ext[268 * 24 + idx] = 0;  // rows 268..279
    }
    __syncthreads();

    // ---- phase C: conv2 MFMA + relu + pool -> y2loc (132 nodes: r0-2 .. r0+129)
    {
        const float bv0 = c2b[m], bv1 = c2b[16 + m];
        for (int mt = wave; mt < 17; mt += 4) {
            f32x4 a0 = {}, a1 = {};
            #pragma unroll
            for (int ks = 0; ks < 3; ks++) {
                const int row = mt * 16 + m + ks * 2 + (q >> 1);
                const bf16x8 af = *(const bf16x8*)(y1ext + row * 24 + (q & 1) * 8);
                a0 = __builtin_amdgcn_mfma_f32_16x16x32_bf16(af, wfC[ks][0], a0, 0, 0, 0);
                a1 = __builtin_amdgcn_mfma_f32_16x16x32_bf16(af, wfC[ks][1], a1, 0, 0, 0);
            }
            const int nrow = mt * 8 + q * 2;
            if (nrow < 132) {
                y2loc[nrow * 40 + m]      = f2bf1(fmaxf(fmaxf(a0[0], a0[1]) + bv0, 0.f));
                y2loc[nrow * 40 + 16 + m] = f2bf1(fmaxf(fmaxf(a1[0], a1[1]) + bv1, 0.f));
            }
            if (nrow + 1 < 132) {
                y2loc[(nrow + 1) * 40 + m]      = f2bf1(fmaxf(fmaxf(a0[2], a0[3]) + bv0, 0.f));
                y2loc[(nrow + 1) * 40 + 16 + m] = f2bf1(fmaxf(fmaxf(a1[2], a1[3]) + bv1, 0.f));
            }
        }
    }
    // gcn1 A-frags (prebuilt, coalesced) while conv2 drains
    bf16x8 wfE[2];
    wfE[0] = *(const bf16x8*)(Wb1 + (ft0 * 64 + lane) * 8);
    wfE[1] = *(const bf16x8*)(Wb1 + ((ft0 + 1) * 64 + lane) * 8);
    __syncthreads();

    // ---- phase D (gcn1 aggregation, VALU stencil): As1 row i <-> node r0-1+i (i<130)
    for (int s = tid; s < 288; s += 256) {
        const int i = s >> 1, fh = (s & 1) * 16;
        unsigned short* dst = As1 + i * 40 + fh;
        const int r = r0 - 1 + i;
        union { us8 v; unsigned int u[4]; } o0, o1;
        if (i >= 130 || r < 0 || r >= RT_) {
            o0.u[0] = o0.u[1] = o0.u[2] = o0.u[3] = 0;
            o1.u[0] = o1.u[1] = o1.u[2] = o1.u[3] = 0;
        } else {
            const float dm = dinv_of(r), cm = dm * dm;
            const unsigned short* Yc = y2loc + (i + 1) * 40 + fh;
            us8 c0 = *(const us8*)(Yc), c1 = *(const us8*)(Yc + 8);
            float v[16];
            #pragma unroll
            for (int j = 0; j < 8; j++) { v[j] = cm * bf2f(c0[j]); v[8 + j] = cm * bf2f(c1[j]); }
            if (r > 0) {
                const float cl = dm * dinv_of(r - 1);
                us8 a0 = *(const us8*)(Yc - 40), a1 = *(const us8*)(Yc - 32);
                #pragma unroll
                for (int j = 0; j < 8; j++) { v[j] += cl * bf2f(a0[j]); v[8 + j] += cl * bf2f(a1[j]); }
            }
            if (r < RT_ - 1) {
                const float cr = dm * dinv_of(r + 1);
                us8 a0 = *(const us8*)(Yc + 40), a1 = *(const us8*)(Yc + 48);
                #pragma unroll
                for (int j = 0; j < 8; j++) { v[j] += cr * bf2f(a0[j]); v[8 + j] += cr * bf2f(a1[j]); }
            }
            #pragma unroll
            for (int i2 = 0; i2 < 4; i2++) {
                o0.u[i2] = f2bf2(v[2 * i2], v[2 * i2 + 1]);
                o1.u[i2] = f2bf2(v[8 + 2 * i2], v[9 + 2 * i2]);
            }
        }
        *(us8*)dst = o0.v; *(us8*)(dst + 8) = o1.v;
    }
    // gcn2 B-frags (prebuilt, coalesced) during phase D
    bf16x8 bw[4][2];
    #pragma unroll
    for (int ks = 0; ks < 4; ks++)
        #pragma unroll
        for (int i = 0; i < 2; i++)
            bw[ks][i] = *(const bf16x8*)(Wb2 + ((size_t)((ks * 8 + wave * 2 + i) * 64 + lane)) * 8);
    // biases from global (loop-invariant; L2-resident): no LDS needed
    const float4 bv0 = *(const float4*)&g1b[ft0 * 16 + q * 4];
    const float4 bv1 = *(const float4*)&g1b[(ft0 + 1) * 16 + q * 4];
    const float bb0 = g2b[wave * 32 + m];
    const float bb1 = g2b[wave * 32 + 16 + m];
    __syncthreads();

    const f32x4 zz = {};

    // E(qi): H slab rows 0..33 <-> nodes r0+qi*32-1 .. r0+qi*32+32, from As1 rows
    // qi*32 .. qi*32+47 (tiles of 16, rows >=34 masked). Halo rows at sample
    // edges hold relu(b1) garbage; F zeroes them via cl/cr coefficients.
    auto do_E = [&](int qi) {
        #pragma unroll
        for (int nt = 0; nt < 3; nt++) {
            const bf16x8 bfr = *(const bf16x8*)(As1 + (qi * 32 + nt * 16 + m) * 40 + q * 8);
            f32x4 o0 = __builtin_amdgcn_mfma_f32_16x16x32_bf16(wfE[0], bfr, zz, 0, 0, 0);
            f32x4 o1 = __builtin_amdgcn_mfma_f32_16x16x32_bf16(wfE[1], bfr, zz, 0, 0, 0);
            const int hrow = nt * 16 + m;
            if (hrow < 34) {
                union { ushort4 s; unsigned int u[2]; } w0, w1;
                w0.u[0] = f2bf2(fmaxf(o0[0] + bv0.x, 0.f), fmaxf(o0[1] + bv0.y, 0.f));
                w0.u[1] = f2bf2(fmaxf(o0[2] + bv0.z, 0.f), fmaxf(o0[3] + bv0.w, 0.f));
                w1.u[0] = f2bf2(fmaxf(o1[0] + bv1.x, 0.f), fmaxf(o1[1] + bv1.y, 0.f));
                w1.u[1] = f2bf2(fmaxf(o1[2] + bv1.z, 0.f), fmaxf(o1[3] + bv1.w, 0.f));
                *(ushort4*)(Hq + hrow * 136 + ft0 * 16 + q * 4) = w0.s;
                *(ushort4*)(Hq + hrow * 136 + (ft0 + 1) * 16 + q * 4) = w1.s;
            }
        }
    };

    do_E(0);
    __syncthreads();

    float s0 = 0.f, s1 = 0.f;
    for (int qi = 0; qi < 4; qi++) {
        // F(qi): VALU stencil Hq -> A2q (32 nodes x 128 feats)
        {
            const int jl = tid >> 3, fh = (tid & 7) * 16;
            const int r = r0 + qi * 32 + jl;
            const float dm = dinv_of(r), cm = dm * dm;
            const float cl = (r > 0) ? dm * dinv_of(r - 1) : 0.f;
            const float cr = (r < RT_ - 1) ? dm * dinv_of(r + 1) : 0.f;
            const unsigned short* Hl = Hq + jl * 136 + fh;
            const unsigned short* Hc = Hl + 136;
            const unsigned short* Hr = Hc + 136;
            unsigned short* dst = A2q + jl * 136 + fh;
            #pragma unroll
            for (int c = 0; c < 2; c++) {
                us8 cc = *(const us8*)(Hc + c * 8);
                us8 ll = *(const us8*)(Hl + c * 8);
                us8 rr = *(const us8*)(Hr + c * 8);
                float v[8];
                #pragma unroll
                for (int e = 0; e < 8; e++)
                    v[e] = cm * bf2f(cc[e]) + cl * bf2f(ll[e]) + cr * bf2f(rr[e]);
                union { us8 v; unsigned int u[4]; } o;
                #pragma unroll
                for (int i2 = 0; i2 < 4; i2++) o.u[i2] = f2bf2(v[2 * i2], v[2 * i2 + 1]);
                *(us8*)(dst + c * 8) = o.v;
            }
        }
        __syncthreads();

        // G(qi): gcn2 for this quarter's 2 node-tiles, FULL K=128 -> acc complete;
        // reduce immediately (acc never persists across quarters)
        {
            f32x4 acc2[2][2] = {};
            #pragma unroll
            for (int ntl = 0; ntl < 2; ntl++)
                #pragma unroll
                for (int ks = 0; ks < 4; ks++) {
                    const bf16x8 af = *(const bf16x8*)(A2q + (ntl * 16 + m) * 136 + ks * 32 + q * 8);
                    acc2[ntl][0] = __builtin_amdgcn_mfma_f32_16x16x32_bf16(af, bw[ks][0], acc2[ntl][0], 0, 0, 0);
                    acc2[ntl][1] = __builtin_amdgcn_mfma_f32_16x16x32_bf16(af, bw[ks][1], acc2[ntl][1], 0, 0, 0);
                }
            #pragma unroll
            for (int ntl = 0; ntl < 2; ntl++)
                #pragma unroll
                for (int rgi = 0; rgi < 4; rgi++) {
                    s0 += fmaxf(acc2[ntl][0][rgi] + bb0, 0.f);
                    s1 += fmaxf(acc2[ntl][1][rgi] + bb1, 0.f);
                }
        }
        // E(qi+1) shares this barrier interval with G (disjoint LDS: Hq vs A2q)
        if (qi < 3) {
            do_E(qi + 1);
            __syncthreads();
        }
    }

    // ---- epilogue: wave-reduce column sums, plain stores (no atomics)
    {
        s0 += __shfl_xor(s0, 16, 64); s0 += __shfl_xor(s0, 32, 64);
        s1 += __shfl_xor(s1, 16, 64); s1 += __shfl_xor(s1, 32, 64);
        if (lane < 16) {
            float* p = partials + (size_t)blockIdx.x * 128 + wave * 32;
            p[m] = s0;
            p[16 + m] = s1;
        }
    }
}

// ---------- kernel 5: mean over RT + FC ----------
__global__ __launch_bounds__(128) void fc_kernel(
    const float* __restrict__ partials, const float* __restrict__ fw,
    const float* __restrict__ fb, float* __restrict__ out)
{
    __shared__ float sm[128];
    const int b = blockIdx.x, tid = threadIdx.x;
    float s = 0.f;
    #pragma unroll
    for (int t = 0; t < 4; t++) s += partials[((b << 2) + t) * 128 + tid];
    sm[tid] = s * (1.0f / 512.0f);
    __syncthreads();
    if (tid < 64) {
        float acc = fb[tid];
        #pragma unroll 8
        for (int f = 0; f < 128; f++) acc += sm[f] * fw[f * 64 + tid];
        out[b * 64 + tid] = acc;
    }
}

extern "C" void kernel_launch(void* const* d_in, const int* in_sizes, int n_in,
                              void* d_out, int out_size, void* d_ws, size_t ws_size,
                              hipStream_t stream)
{
    const float* x   = (const float*)d_in[0];
    const float* w1  = (const float*)d_in[1];
    const float* b1  = (const float*)d_in[2];
    const float* w2  = (const float*)d_in[3];
    const float* b2  = (const float*)d_in[4];
    const float* g1w = (const float*)d_in[5];
    const float* g1b = (const float*)d_in[6];
    const float* g2w = (const float*)d_in[7];
    const float* g2b = (const float*)d_in[8];
    const float* fw  = (const float*)d_in[9];
    const float* fb  = (const float*)d_in[10];

    char* ws = (char*)d_ws;
    float* partials     = (float*)(ws);                           // [B][4][128] fp32 = 2MB
    unsigned short* Wb1 = (unsigned short*)(ws + 2097152);        // 4096 elems
    unsigned short* Wb2 = (unsigned short*)(ws + 2097152 + 16384);// 16384 elems
    unsigned short* Wc1 = (unsigned short*)(ws + 2097152 + 65536);// 1536 elems
    unsigned short* Wc2 = (unsigned short*)(ws + 2097152 + 81920);// 3072 elems
    float* out = (float*)d_out;

    repack_w<<<32, 256, 0, stream>>>(g1w, g2w, w1, w2, Wb1, Wb2, Wc1, Wc2);
    mega<<<NNODES / 128, 256, 0, stream>>>(x, Wc1, Wc2, Wb1, Wb2,
                                           b1, b2, g1b, g2b, partials);
    fc_kernel<<<B_, 128, 0, stream>>>(partials, fw, fb, out);
}